// Round 2
// baseline (259.043 us; speedup 1.0000x reference)
//
#include <hip/hip_runtime.h>
#include <stdint.h>

typedef unsigned short u16;
typedef short bf16x8 __attribute__((ext_vector_type(8)));
typedef float f32x4 __attribute__((ext_vector_type(4)));

#define MFMA16(a, b, c) __builtin_amdgcn_mfma_f32_16x16x32_bf16((a), (b), (c), 0, 0, 0)

__device__ __forceinline__ u16 f2bf(float f) {
  union { float f; unsigned int u; } v; v.f = f;
  unsigned int u = v.u;
  unsigned int r = (u + 0x7FFFu + ((u >> 16) & 1u)) >> 16;  // RNE
  return (u16)r;
}

// async global->LDS, 16B per lane. LDS base must be wave-uniform (HW adds lane*16).
__device__ __forceinline__ void gload_lds16(const void* g, void* l) {
  __builtin_amdgcn_global_load_lds(
      (const __attribute__((address_space(1))) unsigned int*)g,
      (__attribute__((address_space(3))) unsigned int*)l,
      16, 0, 0);
}

// ---------------- convert fp32 -> bf16 (vectorized) ----------------
__global__ __launch_bounds__(256) void cvt_f32_bf16(
    const float* __restrict__ src, u16* __restrict__ dst, int n4) {
  int i = blockIdx.x * 256 + threadIdx.x;
  if (i >= n4) return;
  float4 v = reinterpret_cast<const float4*>(src)[i];
  ushort4 o;
  o.x = f2bf(v.x); o.y = f2bf(v.y); o.z = f2bf(v.z); o.w = f2bf(v.w);
  reinterpret_cast<ushort4*>(dst)[i] = o;
}

// ---------------- transpose+convert: src f32 [R][C] -> dst bf16 [C][R] ----------------
__global__ __launch_bounds__(256) void transpose_f32_bf16(
    const float* __restrict__ src, u16* __restrict__ dst, int R, int C) {
  __shared__ u16 t[32][33];
  const int bx = blockIdx.x * 32, by = blockIdx.y * 32;
  const int tx = threadIdx.x & 31, ty = threadIdx.x >> 5;  // 32x8
#pragma unroll
  for (int i = 0; i < 32; i += 8)
    t[ty + i][tx] = f2bf(src[(size_t)(by + ty + i) * C + bx + tx]);
  __syncthreads();
#pragma unroll
  for (int i = 0; i < 32; i += 8)
    dst[(size_t)(bx + ty + i) * R + by + tx] = t[tx][ty + i];
}

// ---------------- GEMM: C[M][N] = A[M][K] * Bt[N][K]^T + bias ----------------
// 128x128 tile, BK=64, 4 waves (2x2), 16x16x32 bf16 MFMA, global_load_lds staging.
template <bool OUT_BF16>
__global__ __launch_bounds__(256) void gemm_bf16(
    const u16* __restrict__ A, const u16* __restrict__ Bt,
    const float* __restrict__ bias, void* __restrict__ Cout,
    int M, int N, int K) {
  __shared__ __align__(16) u16 As[128 * 64];
  __shared__ __align__(16) u16 Bs[128 * 64];
  const int tid = threadIdx.x;
  const int lane = tid & 63;
  const int wave = tid >> 6;
  const int m0 = blockIdx.y * 128;
  const int n0 = blockIdx.x * 128;
  const int wm = (wave >> 1) * 64;
  const int wn = (wave & 1) * 64;

  f32x4 acc[4][4] = {};

  const char* Abase = (const char*)A;
  const char* Bbase = (const char*)Bt;

  for (int kt = 0; kt < K; kt += 64) {
    __syncthreads();  // protect LDS from readers of previous tile
#pragma unroll
    for (int i = 0; i < 4; ++i) {
      int flat = wave * 1024 + lane * 16 + i * 4096;  // byte offset in 16KB tile
      int row = flat >> 7;                            // 128B per row (64 bf16)
      int colb = flat & 127;
      gload_lds16(Abase + ((size_t)(m0 + row) * K + kt) * 2 + colb,
                  (char*)As + wave * 1024 + i * 4096);
      gload_lds16(Bbase + ((size_t)(n0 + row) * K + kt) * 2 + colb,
                  (char*)Bs + wave * 1024 + i * 4096);
    }
    __syncthreads();  // drains vmcnt (global_load_lds)
#pragma unroll
    for (int ks = 0; ks < 2; ++ks) {
      const int col = (lane >> 4) * 8 + ks * 32;
      bf16x8 af[4], bfr[4];
#pragma unroll
      for (int mt = 0; mt < 4; ++mt)
        af[mt] = *(const bf16x8*)(As + (wm + mt * 16 + (lane & 15)) * 64 + col);
#pragma unroll
      for (int nt = 0; nt < 4; ++nt)
        bfr[nt] = *(const bf16x8*)(Bs + (wn + nt * 16 + (lane & 15)) * 64 + col);
#pragma unroll
      for (int mt = 0; mt < 4; ++mt)
#pragma unroll
        for (int nt = 0; nt < 4; ++nt)
          acc[mt][nt] = MFMA16(af[mt], bfr[nt], acc[mt][nt]);
    }
  }

  float bv[4];
#pragma unroll
  for (int nt = 0; nt < 4; ++nt)
    bv[nt] = bias[n0 + wn + nt * 16 + (lane & 15)];
#pragma unroll
  for (int mt = 0; mt < 4; ++mt)
#pragma unroll
    for (int nt = 0; nt < 4; ++nt)
#pragma unroll
      for (int r = 0; r < 4; ++r) {
        int m = m0 + wm + mt * 16 + (lane >> 4) * 4 + r;
        int n = n0 + wn + nt * 16 + (lane & 15);
        float v = acc[mt][nt][r] + bv[nt];
        if (OUT_BF16)
          ((u16*)Cout)[(size_t)m * N + n] = f2bf(v);
        else
          ((float*)Cout)[(size_t)m * N + n] = v;
      }
}

// ---------------- flash attention ----------------
// qkv[B*T][3072] bf16: q at col h*64, k at 1024+h*64, v at 2048+h*64.
// grid (T/128, 16 heads, B); 4 waves x 32 q-rows; KV tiles of 64 keys.
#define T_SEQ 2048
#define ROWQKV 3072

__global__ __launch_bounds__(256) void attn_fwd(
    const u16* __restrict__ qkv, const int* __restrict__ mask,
    u16* __restrict__ att) {
  __shared__ __align__(16) u16 Ks[64 * 64];     // [key][dk] linear (global_load_lds)
  __shared__ __align__(16) u16 Vt[64 * 72];     // [d][key] padded (reg-transposed)
  __shared__ __align__(16) u16 Ps[4][32 * 72];  // per-wave P tile [q][key] padded
  __shared__ u16 mk[T_SEQ];

  const int tid = threadIdx.x;
  const int lane = tid & 63;
  const int wave = tid >> 6;
  const int h = blockIdx.y;
  const int b = blockIdx.z;
  const int q0 = blockIdx.x * 128 + wave * 32;
  const size_t rowb = (size_t)b * T_SEQ;

  for (int i = tid; i < T_SEQ; i += 256)
    mk[i] = (u16)(mask[b * T_SEQ + i] != 0);

  // hoist Q fragments to registers (A-operand of QK^T)
  bf16x8 aq[2][2];
#pragma unroll
  for (int mt = 0; mt < 2; ++mt)
#pragma unroll
    for (int ks = 0; ks < 2; ++ks)
      aq[mt][ks] = *(const bf16x8*)(qkv +
          (rowb + q0 + mt * 16 + (lane & 15)) * ROWQKV +
          h * 64 + (lane >> 4) * 8 + ks * 32);

  float mrun[2][4], lrun[2][4];
  f32x4 accO[2][4] = {};
#pragma unroll
  for (int mt = 0; mt < 2; ++mt)
#pragma unroll
    for (int r = 0; r < 4; ++r) { mrun[mt][r] = -INFINITY; lrun[mt][r] = 0.f; }

  for (int kt = 0; kt < T_SEQ; kt += 64) {
    __syncthreads();
    // stage K tile [64][64] via global_load_lds (8KB = 2 issues/wave)
#pragma unroll
    for (int i = 0; i < 2; ++i) {
      int flat = wave * 1024 + lane * 16 + i * 4096;
      int krow = flat >> 7;
      int colb = flat & 127;
      gload_lds16((const char*)qkv +
                      ((rowb + kt + krow) * ROWQKV + 1024 + h * 64) * 2 + colb,
                  (char*)Ks + wave * 1024 + i * 4096);
    }
    // stage V transposed: Vt[d][key], pad 72 to spread banks
#pragma unroll
    for (int i = 0; i < 2; ++i) {
      int c = tid + i * 256;  // 512 chunks of 8 bf16
      int key = c >> 3;
      int d0 = (c & 7) * 8;
      bf16x8 v = *(const bf16x8*)(qkv + (rowb + kt + key) * ROWQKV + 2048 + h * 64 + d0);
#pragma unroll
      for (int j = 0; j < 8; ++j)
        Vt[(d0 + j) * 72 + key] = (u16)v[j];
    }
    __syncthreads();

    // S = Q K^T  (C-layout: key = lane&15 within nt tile, q = (lane>>4)*4+r)
    f32x4 s[2][4] = {};
#pragma unroll
    for (int ks = 0; ks < 2; ++ks) {
      const int col = (lane >> 4) * 8 + ks * 32;
      bf16x8 bk[4];
#pragma unroll
      for (int nt = 0; nt < 4; ++nt)
        bk[nt] = *(const bf16x8*)(Ks + (nt * 16 + (lane & 15)) * 64 + col);
#pragma unroll
      for (int mt = 0; mt < 2; ++mt)
#pragma unroll
        for (int nt = 0; nt < 4; ++nt)
          s[mt][nt] = MFMA16(aq[mt][ks], bk[nt], s[mt][nt]);
    }
    // scale + mask (mask is key-only)
#pragma unroll
    for (int nt = 0; nt < 4; ++nt) {
      bool keep = mk[kt + nt * 16 + (lane & 15)] != 0;
#pragma unroll
      for (int mt = 0; mt < 2; ++mt)
#pragma unroll
        for (int r = 0; r < 4; ++r)
          s[mt][nt][r] = keep ? s[mt][nt][r] * 0.125f : -1e9f;
    }
    // online softmax per q-row (16-lane key groups)
#pragma unroll
    for (int mt = 0; mt < 2; ++mt)
#pragma unroll
      for (int r = 0; r < 4; ++r) {
        float mx = fmaxf(fmaxf(s[mt][0][r], s[mt][1][r]),
                         fmaxf(s[mt][2][r], s[mt][3][r]));
#pragma unroll
        for (int sh = 1; sh < 16; sh <<= 1)
          mx = fmaxf(mx, __shfl_xor(mx, sh));
        float mo = mrun[mt][r];
        float mn = fmaxf(mo, mx);
        float fac = __expf(mo - mn);  // exp(-inf)=0 on first tile
        float rs = 0.f;
#pragma unroll
        for (int nt = 0; nt < 4; ++nt) {
          float p = __expf(s[mt][nt][r] - mn);
          s[mt][nt][r] = p;
          rs += p;
        }
#pragma unroll
        for (int sh = 1; sh < 16; sh <<= 1)
          rs += __shfl_xor(rs, sh);
        mrun[mt][r] = mn;
        lrun[mt][r] = lrun[mt][r] * fac + rs;
#pragma unroll
        for (int nt = 0; nt < 4; ++nt)
          accO[mt][nt][r] *= fac;
      }
    // write P (bf16) to per-wave LDS region; same wave consumes -> no barrier
    u16* Pw = &Ps[wave][0];
#pragma unroll
    for (int mt = 0; mt < 2; ++mt)
#pragma unroll
      for (int nt = 0; nt < 4; ++nt)
#pragma unroll
        for (int r = 0; r < 4; ++r)
          Pw[(mt * 16 + (lane >> 4) * 4 + r) * 72 + nt * 16 + (lane & 15)] =
              f2bf(s[mt][nt][r]);
    // O += P V
#pragma unroll
    for (int ks = 0; ks < 2; ++ks) {
      const int col = (lane >> 4) * 8 + ks * 32;
      bf16x8 ap[2], bv[4];
#pragma unroll
      for (int mt = 0; mt < 2; ++mt)
        ap[mt] = *(const bf16x8*)(Pw + (mt * 16 + (lane & 15)) * 72 + col);
#pragma unroll
      for (int nt = 0; nt < 4; ++nt)
        bv[nt] = *(const bf16x8*)(Vt + (nt * 16 + (lane & 15)) * 72 + col);
#pragma unroll
      for (int mt = 0; mt < 2; ++mt)
#pragma unroll
        for (int nt = 0; nt < 4; ++nt)
          accO[mt][nt] = MFMA16(ap[mt], bv[nt], accO[mt][nt]);
    }
  }

  // epilogue: divide by l, store att[b*T+q][h*64+d]
#pragma unroll
  for (int mt = 0; mt < 2; ++mt)
#pragma unroll
    for (int r = 0; r < 4; ++r) {
      float inv = 1.f / lrun[mt][r];
#pragma unroll
      for (int nt = 0; nt < 4; ++nt) {
        int q = q0 + mt * 16 + (lane >> 4) * 4 + r;
        int d = h * 64 + nt * 16 + (lane & 15);
        att[(rowb + q) * 1024 + d] = f2bf(accO[mt][nt][r] * inv);
      }
    }
}

// ---------------- launch ----------------
extern "C" void kernel_launch(void* const* d_in, const int* in_sizes, int n_in,
                              void* d_out, int out_size, void* d_ws, size_t ws_size,
                              hipStream_t stream) {
  const float* x = (const float*)d_in[0];     // [2,2048,1024] f32
  const int* mask = (const int*)d_in[1];      // [2,1,1,2048] int32
  const float* Wqkv = (const float*)d_in[2];  // [1024,3072] f32
  const float* bqkv = (const float*)d_in[3];  // [3072] f32
  const float* Wout = (const float*)d_in[4];  // [1024,1024] f32
  const float* bout = (const float*)d_in[5];  // [1024] f32
  float* out = (float*)d_out;                 // [2,2048,1024] f32

  const int B = 2, T = 2048, H = 1024, M = B * T;

  // ws layout (bf16 elems): qkv 25.2MB | xa (x-bf16, later reused as att) 8.4MB |
  //                         WtQ 6.3MB | WtO 2.1MB   => 40MB total
  u16* qkv = (u16*)d_ws;
  u16* xa = qkv + (size_t)M * 3 * H;
  u16* WtQ = xa + (size_t)M * H;
  u16* WtO = WtQ + (size_t)3 * H * H;

  cvt_f32_bf16<<<(M * H / 4 + 255) / 256, 256, 0, stream>>>(x, xa, M * H / 4);
  transpose_f32_bf16<<<dim3(3 * H / 32, H / 32), 256, 0, stream>>>(Wqkv, WtQ, H, 3 * H);
  transpose_f32_bf16<<<dim3(H / 32, H / 32), 256, 0, stream>>>(Wout, WtO, H, H);
  gemm_bf16<true><<<dim3(3 * H / 128, M / 128), 256, 0, stream>>>(xa, WtQ, bqkv, qkv, M, 3 * H, H);
  attn_fwd<<<dim3(T / 128, 16, B), 256, 0, stream>>>(qkv, mask, xa);  // att reuses xa
  gemm_bf16<false><<<dim3(H / 128, M / 128), 256, 0, stream>>>(xa, WtO, bout, out, M, H, H);
}

// Round 3
// 227.909 us; speedup vs baseline: 1.1366x; 1.1366x over previous
//
#include <hip/hip_runtime.h>
#include <stdint.h>

typedef unsigned short u16;
typedef short bf16x8 __attribute__((ext_vector_type(8)));
typedef float f32x4 __attribute__((ext_vector_type(4)));

#define MFMA16(a, b, c) __builtin_amdgcn_mfma_f32_16x16x32_bf16((a), (b), (c), 0, 0, 0)

__device__ __forceinline__ u16 f2bf(float f) {
  union { float f; unsigned int u; } v; v.f = f;
  unsigned int u = v.u;
  unsigned int r = (u + 0x7FFFu + ((u >> 16) & 1u)) >> 16;  // RNE
  return (u16)r;
}

// async global->LDS, 16B per lane. LDS base must be wave-uniform (HW adds lane*16).
__device__ __forceinline__ void gload_lds16(const void* g, void* l) {
  __builtin_amdgcn_global_load_lds(
      (const __attribute__((address_space(1))) unsigned int*)g,
      (__attribute__((address_space(3))) unsigned int*)l,
      16, 0, 0);
}

// ---------------- convert fp32 -> bf16 (vectorized) ----------------
__global__ __launch_bounds__(256) void cvt_f32_bf16(
    const float* __restrict__ src, u16* __restrict__ dst, int n4) {
  int i = blockIdx.x * 256 + threadIdx.x;
  if (i >= n4) return;
  float4 v = reinterpret_cast<const float4*>(src)[i];
  ushort4 o;
  o.x = f2bf(v.x); o.y = f2bf(v.y); o.z = f2bf(v.z); o.w = f2bf(v.w);
  reinterpret_cast<ushort4*>(dst)[i] = o;
}

// ---------------- transpose+convert: src f32 [R][C] -> dst bf16 [C][R] ----------------
__global__ __launch_bounds__(256) void transpose_f32_bf16(
    const float* __restrict__ src, u16* __restrict__ dst, int R, int C) {
  __shared__ u16 t[32][33];
  const int bx = blockIdx.x * 32, by = blockIdx.y * 32;
  const int tx = threadIdx.x & 31, ty = threadIdx.x >> 5;  // 32x8
#pragma unroll
  for (int i = 0; i < 32; i += 8)
    t[ty + i][tx] = f2bf(src[(size_t)(by + ty + i) * C + bx + tx]);
  __syncthreads();
#pragma unroll
  for (int i = 0; i < 32; i += 8)
    dst[(size_t)(bx + ty + i) * R + by + tx] = t[tx][ty + i];
}

// ---------------- GEMM: C[M][N] = A[M][K] * Bt[N][K]^T + bias ----------------
// 128x128 tile, BK=64, 4 waves (2x2), 16x16x32 bf16 MFMA, global_load_lds staging.
template <bool OUT_BF16>
__global__ __launch_bounds__(256) void gemm_bf16(
    const u16* __restrict__ A, const u16* __restrict__ Bt,
    const float* __restrict__ bias, void* __restrict__ Cout,
    int M, int N, int K) {
  __shared__ __align__(16) u16 As[128 * 64];
  __shared__ __align__(16) u16 Bs[128 * 64];
  const int tid = threadIdx.x;
  const int lane = tid & 63;
  const int wave = tid >> 6;
  const int m0 = blockIdx.y * 128;
  const int n0 = blockIdx.x * 128;
  const int wm = (wave >> 1) * 64;
  const int wn = (wave & 1) * 64;

  f32x4 acc[4][4] = {};

  const char* Abase = (const char*)A;
  const char* Bbase = (const char*)Bt;

  for (int kt = 0; kt < K; kt += 64) {
    __syncthreads();
#pragma unroll
    for (int i = 0; i < 4; ++i) {
      int flat = wave * 1024 + lane * 16 + i * 4096;
      int row = flat >> 7;
      int colb = flat & 127;
      gload_lds16(Abase + ((size_t)(m0 + row) * K + kt) * 2 + colb,
                  (char*)As + wave * 1024 + i * 4096);
      gload_lds16(Bbase + ((size_t)(n0 + row) * K + kt) * 2 + colb,
                  (char*)Bs + wave * 1024 + i * 4096);
    }
    __syncthreads();
#pragma unroll
    for (int ks = 0; ks < 2; ++ks) {
      const int col = (lane >> 4) * 8 + ks * 32;
      bf16x8 af[4], bfr[4];
#pragma unroll
      for (int mt = 0; mt < 4; ++mt)
        af[mt] = *(const bf16x8*)(As + (wm + mt * 16 + (lane & 15)) * 64 + col);
#pragma unroll
      for (int nt = 0; nt < 4; ++nt)
        bfr[nt] = *(const bf16x8*)(Bs + (wn + nt * 16 + (lane & 15)) * 64 + col);
#pragma unroll
      for (int mt = 0; mt < 4; ++mt)
#pragma unroll
        for (int nt = 0; nt < 4; ++nt)
          acc[mt][nt] = MFMA16(af[mt], bfr[nt], acc[mt][nt]);
    }
  }

  float bv[4];
#pragma unroll
  for (int nt = 0; nt < 4; ++nt)
    bv[nt] = bias[n0 + wn + nt * 16 + (lane & 15)];
#pragma unroll
  for (int mt = 0; mt < 4; ++mt)
#pragma unroll
    for (int nt = 0; nt < 4; ++nt)
#pragma unroll
      for (int r = 0; r < 4; ++r) {
        int m = m0 + wm + mt * 16 + (lane >> 4) * 4 + r;
        int n = n0 + wn + nt * 16 + (lane & 15);
        float v = acc[mt][nt][r] + bv[nt];
        if (OUT_BF16)
          ((u16*)Cout)[(size_t)m * N + n] = f2bf(v);
        else
          ((float*)Cout)[(size_t)m * N + n] = v;
      }
}

// ---------------- flash attention (v3: swizzled LDS + 2-phase pipeline) ----------------
// qkv[B*T][3072] bf16: q at col h*64, k at 1024+h*64, v at 2048+h*64.
// grid (T/128, 16 heads, B); 4 waves x 32 q-rows; KV tiles of 64 keys, double-buffered.
#define T_SEQ 2048
#define ROWQKV 3072
#define SCL 0.180336880f  /* (1/sqrt(64)) * log2(e) */

__global__ __launch_bounds__(256) void attn_fwd(
    const u16* __restrict__ qkv, const int* __restrict__ mask,
    u16* __restrict__ att) {
  __shared__ __align__(16) u16 Ks[2][64 * 64];  // [key][dk], XOR-swizzled s=row&7
  __shared__ __align__(16) u16 Vt[2][64 * 64];  // [d][key],  XOR-swizzled s=row^(row>>3)
  __shared__ __align__(16) u16 Ps[4][32 * 72];  // per-wave P tile [q][key] padded
  __shared__ u16 mk[T_SEQ];

  const int tid = threadIdx.x;
  const int lane = tid & 63;
  const int wave = tid >> 6;
  const int r15 = lane & 15;
  const int g = lane >> 4;
  const int h = blockIdx.y;
  const int b = blockIdx.z;
  const int q0 = blockIdx.x * 128 + wave * 32;
  const size_t rowb = (size_t)b * T_SEQ;

  for (int i = tid; i < T_SEQ; i += 256)
    mk[i] = (u16)(mask[b * T_SEQ + i] != 0);

  // hoist Q fragments (A-operand of QK^T)
  bf16x8 aq[2][2];
#pragma unroll
  for (int mt = 0; mt < 2; ++mt)
#pragma unroll
    for (int ks = 0; ks < 2; ++ks)
      aq[mt][ks] = *(const bf16x8*)(qkv +
          (rowb + q0 + mt * 16 + r15) * ROWQKV + h * 64 + g * 8 + ks * 32);

  float mrun[2][4], lrun[2][4];
  f32x4 accO[2][4] = {};
#pragma unroll
  for (int mt = 0; mt < 2; ++mt)
#pragma unroll
    for (int r = 0; r < 4; ++r) { mrun[mt][r] = -INFINITY; lrun[mt][r] = 0.f; }

  bf16x8 vr0, vr1;  // V prefetch registers (2 x 16B per thread = 8KB/block)

  // --- staging helpers (inlined via macros to keep indices compile-time) ---
#define ISSUE_K(ktile, buf)                                                    \
  _Pragma("unroll") for (int i = 0; i < 2; ++i) {                              \
    int L = wave * 1024 + i * 4096 + lane * 16;                                \
    int row = L >> 7;                                                          \
    int cb = L & 127;                                                          \
    int scb = cb ^ ((row & 7) << 4); /* pre-swizzled global source */          \
    gload_lds16((const char*)qkv +                                             \
                    ((rowb + (ktile) + row) * ROWQKV + 1024 + h * 64) * 2 + scb, \
                (char*)&Ks[buf][0] + wave * 1024 + i * 4096);                  \
  }

#define LOAD_V(ktile)                                                          \
  {                                                                            \
    int c0 = tid, c1 = tid + 256;                                              \
    vr0 = *(const bf16x8*)(qkv + (rowb + (ktile) + (c0 >> 3)) * ROWQKV +       \
                           2048 + h * 64 + (c0 & 7) * 8);                      \
    vr1 = *(const bf16x8*)(qkv + (rowb + (ktile) + (c1 >> 3)) * ROWQKV +       \
                           2048 + h * 64 + (c1 & 7) * 8);                      \
  }

#define WRITE_V(buf)                                                           \
  _Pragma("unroll") for (int j = 0; j < 8; ++j) {                              \
    int d0 = (tid & 7) * 8;                                                    \
    int row = d0 + j;                                                          \
    int sv = ((row ^ (row >> 3)) & 7) << 4;                                    \
    *(u16*)((char*)&Vt[buf][0] + row * 128 + (((tid >> 3) * 2) ^ sv)) =        \
        (u16)vr0[j];                                                           \
    *(u16*)((char*)&Vt[buf][0] + row * 128 + ((((tid >> 3) + 32) * 2) ^ sv)) = \
        (u16)vr1[j];                                                           \
  }

  // prologue: stage tile 0
  ISSUE_K(0, 0);
  LOAD_V(0);
  asm volatile("s_waitcnt vmcnt(0)" ::: "memory");
  WRITE_V(0);
  asm volatile("s_waitcnt lgkmcnt(0)" ::: "memory");
  __builtin_amdgcn_sched_barrier(0);
  __builtin_amdgcn_s_barrier();
  __builtin_amdgcn_sched_barrier(0);

  int cur = 0;
  for (int t = 0; t < T_SEQ / 64; ++t) {
    const int kt = t * 64;
    if (t < T_SEQ / 64 - 1) {  // prefetch next tile (flies during compute)
      ISSUE_K(kt + 64, cur ^ 1);
      LOAD_V(kt + 64);
    }

    // S = Q K^T (swizzled K reads: conflict-free)
    f32x4 s[2][4] = {};
#pragma unroll
    for (int ks = 0; ks < 2; ++ks) {
      bf16x8 bk[4];
#pragma unroll
      for (int nt = 0; nt < 4; ++nt) {
        int row = nt * 16 + r15;
        int cb = (g * 8 + ks * 32) * 2;
        bk[nt] = *(const bf16x8*)((const char*)&Ks[cur][0] + row * 128 +
                                  (cb ^ ((row & 7) << 4)));
      }
#pragma unroll
      for (int mt = 0; mt < 2; ++mt)
#pragma unroll
        for (int nt = 0; nt < 4; ++nt)
          s[mt][nt] = MFMA16(aq[mt][ks], bk[nt], s[mt][nt]);
    }
    // scale (incl. log2e) + key mask
#pragma unroll
    for (int nt = 0; nt < 4; ++nt) {
      bool keep = mk[kt + nt * 16 + r15] != 0;
#pragma unroll
      for (int mt = 0; mt < 2; ++mt)
#pragma unroll
        for (int r = 0; r < 4; ++r)
          s[mt][nt][r] = keep ? s[mt][nt][r] * SCL : -1e9f;
    }
    // online softmax per q-row (base-2)
#pragma unroll
    for (int mt = 0; mt < 2; ++mt)
#pragma unroll
      for (int r = 0; r < 4; ++r) {
        float mx = fmaxf(fmaxf(s[mt][0][r], s[mt][1][r]),
                         fmaxf(s[mt][2][r], s[mt][3][r]));
#pragma unroll
        for (int sh = 1; sh < 16; sh <<= 1)
          mx = fmaxf(mx, __shfl_xor(mx, sh));
        float mo = mrun[mt][r];
        float mn = fmaxf(mo, mx);
        float fac = exp2f(mo - mn);
        float rs = 0.f;
#pragma unroll
        for (int nt = 0; nt < 4; ++nt) {
          float p = exp2f(s[mt][nt][r] - mn);
          s[mt][nt][r] = p;
          rs += p;
        }
#pragma unroll
        for (int sh = 1; sh < 16; sh <<= 1)
          rs += __shfl_xor(rs, sh);
        mrun[mt][r] = mn;
        lrun[mt][r] = lrun[mt][r] * fac + rs;
#pragma unroll
        for (int nt = 0; nt < 4; ++nt)
          accO[mt][nt][r] *= fac;
      }
    // P -> per-wave LDS (same wave consumes; compiler inserts lgkm wait)
    u16* Pw = &Ps[wave][0];
#pragma unroll
    for (int mt = 0; mt < 2; ++mt)
#pragma unroll
      for (int nt = 0; nt < 4; ++nt)
#pragma unroll
        for (int r = 0; r < 4; ++r)
          Pw[(mt * 16 + g * 4 + r) * 72 + nt * 16 + r15] = f2bf(s[mt][nt][r]);
    // O += P V (swizzled V reads)
#pragma unroll
    for (int ks = 0; ks < 2; ++ks) {
      const int col = g * 8 + ks * 32;
      bf16x8 ap[2], bv[4];
#pragma unroll
      for (int mt = 0; mt < 2; ++mt)
        ap[mt] = *(const bf16x8*)(Pw + (mt * 16 + r15) * 72 + col);
#pragma unroll
      for (int nt = 0; nt < 4; ++nt) {
        int row = nt * 16 + r15;
        int sv = ((row ^ (row >> 3)) & 7) << 4;
        bv[nt] = *(const bf16x8*)((const char*)&Vt[cur][0] + row * 128 +
                                  ((col * 2) ^ sv));
      }
#pragma unroll
      for (int mt = 0; mt < 2; ++mt)
#pragma unroll
        for (int nt = 0; nt < 4; ++nt)
          accO[mt][nt] = MFMA16(ap[mt], bv[nt], accO[mt][nt]);
    }

    if (t < T_SEQ / 64 - 1) {
      // finish staging of tile t+1, then cross the barrier
      asm volatile("s_waitcnt vmcnt(0)" ::: "memory");
      WRITE_V(cur ^ 1);
      asm volatile("s_waitcnt lgkmcnt(0)" ::: "memory");
      __builtin_amdgcn_sched_barrier(0);
      __builtin_amdgcn_s_barrier();
      __builtin_amdgcn_sched_barrier(0);
      cur ^= 1;
    }
  }

  // epilogue
#pragma unroll
  for (int mt = 0; mt < 2; ++mt)
#pragma unroll
    for (int r = 0; r < 4; ++r) {
      float inv = 1.f / lrun[mt][r];
#pragma unroll
      for (int nt = 0; nt < 4; ++nt) {
        int q = q0 + mt * 16 + g * 4 + r;
        int d = h * 64 + nt * 16 + r15;
        att[(rowb + q) * 1024 + d] = f2bf(accO[mt][nt][r] * inv);
      }
    }
#undef ISSUE_K
#undef LOAD_V
#undef WRITE_V
}

// ---------------- launch ----------------
extern "C" void kernel_launch(void* const* d_in, const int* in_sizes, int n_in,
                              void* d_out, int out_size, void* d_ws, size_t ws_size,
                              hipStream_t stream) {
  const float* x = (const float*)d_in[0];     // [2,2048,1024] f32
  const int* mask = (const int*)d_in[1];      // [2,1,1,2048] int32
  const float* Wqkv = (const float*)d_in[2];  // [1024,3072] f32
  const float* bqkv = (const float*)d_in[3];  // [3072] f32
  const float* Wout = (const float*)d_in[4];  // [1024,1024] f32
  const float* bout = (const float*)d_in[5];  // [1024] f32
  float* out = (float*)d_out;                 // [2,2048,1024] f32

  const int B = 2, T = 2048, H = 1024, M = B * T;

  u16* qkv = (u16*)d_ws;
  u16* xa = qkv + (size_t)M * 3 * H;
  u16* WtQ = xa + (size_t)M * H;
  u16* WtO = WtQ + (size_t)3 * H * H;

  cvt_f32_bf16<<<(M * H / 4 + 255) / 256, 256, 0, stream>>>(x, xa, M * H / 4);
  transpose_f32_bf16<<<dim3(3 * H / 32, H / 32), 256, 0, stream>>>(Wqkv, WtQ, H, 3 * H);
  transpose_f32_bf16<<<dim3(H / 32, H / 32), 256, 0, stream>>>(Wout, WtO, H, H);
  gemm_bf16<true><<<dim3(3 * H / 128, M / 128), 256, 0, stream>>>(xa, WtQ, bqkv, qkv, M, 3 * H, H);
  attn_fwd<<<dim3(T / 128, 16, B), 256, 0, stream>>>(qkv, mask, xa);
  gemm_bf16<false><<<dim3(H / 128, M / 128), 256, 0, stream>>>(xa, WtO, bout, out, M, H, H);
}

// Round 4
// 197.603 us; speedup vs baseline: 1.3109x; 1.1534x over previous
//
#include <hip/hip_runtime.h>
#include <stdint.h>

typedef unsigned short u16;
typedef short bf16x8 __attribute__((ext_vector_type(8)));
typedef float f32x4 __attribute__((ext_vector_type(4)));

#define MFMA16(a, b, c) __builtin_amdgcn_mfma_f32_16x16x32_bf16((a), (b), (c), 0, 0, 0)

__device__ __forceinline__ u16 f2bf(float f) {
  union { float f; unsigned int u; } v; v.f = f;
  unsigned int u = v.u;
  unsigned int r = (u + 0x7FFFu + ((u >> 16) & 1u)) >> 16;  // RNE
  return (u16)r;
}

// async global->LDS, 16B per lane. LDS base must be wave-uniform (HW adds lane*16).
__device__ __forceinline__ void gload_lds16(const void* g, void* l) {
  __builtin_amdgcn_global_load_lds(
      (const __attribute__((address_space(1))) unsigned int*)g,
      (__attribute__((address_space(3))) unsigned int*)l,
      16, 0, 0);
}

// ---------------- convert fp32 -> bf16 (vectorized) ----------------
__global__ __launch_bounds__(256) void cvt_f32_bf16(
    const float* __restrict__ src, u16* __restrict__ dst, int n4) {
  int i = blockIdx.x * 256 + threadIdx.x;
  if (i >= n4) return;
  float4 v = reinterpret_cast<const float4*>(src)[i];
  ushort4 o;
  o.x = f2bf(v.x); o.y = f2bf(v.y); o.z = f2bf(v.z); o.w = f2bf(v.w);
  reinterpret_cast<ushort4*>(dst)[i] = o;
}

// ---------------- transpose+convert: src f32 [R][C] -> dst bf16 [C][R] ----------------
__global__ __launch_bounds__(256) void transpose_f32_bf16(
    const float* __restrict__ src, u16* __restrict__ dst, int R, int C) {
  __shared__ u16 t[32][33];
  const int bx = blockIdx.x * 32, by = blockIdx.y * 32;
  const int tx = threadIdx.x & 31, ty = threadIdx.x >> 5;  // 32x8
#pragma unroll
  for (int i = 0; i < 32; i += 8)
    t[ty + i][tx] = f2bf(src[(size_t)(by + ty + i) * C + bx + tx]);
  __syncthreads();
#pragma unroll
  for (int i = 0; i < 32; i += 8)
    dst[(size_t)(bx + ty + i) * R + by + tx] = t[tx][ty + i];
}

// ---------------- GEMM: C[M][N] = A[M][K] * Bt[N][K]^T + bias ----------------
template <bool OUT_BF16>
__global__ __launch_bounds__(256) void gemm_bf16(
    const u16* __restrict__ A, const u16* __restrict__ Bt,
    const float* __restrict__ bias, void* __restrict__ Cout,
    int M, int N, int K) {
  __shared__ __align__(16) u16 As[128 * 64];
  __shared__ __align__(16) u16 Bs[128 * 64];
  const int tid = threadIdx.x;
  const int lane = tid & 63;
  const int wave = tid >> 6;
  const int m0 = blockIdx.y * 128;
  const int n0 = blockIdx.x * 128;
  const int wm = (wave >> 1) * 64;
  const int wn = (wave & 1) * 64;

  f32x4 acc[4][4] = {};

  const char* Abase = (const char*)A;
  const char* Bbase = (const char*)Bt;

  for (int kt = 0; kt < K; kt += 64) {
    __syncthreads();
#pragma unroll
    for (int i = 0; i < 4; ++i) {
      int flat = wave * 1024 + lane * 16 + i * 4096;
      int row = flat >> 7;
      int colb = flat & 127;
      gload_lds16(Abase + ((size_t)(m0 + row) * K + kt) * 2 + colb,
                  (char*)As + wave * 1024 + i * 4096);
      gload_lds16(Bbase + ((size_t)(n0 + row) * K + kt) * 2 + colb,
                  (char*)Bs + wave * 1024 + i * 4096);
    }
    __syncthreads();
#pragma unroll
    for (int ks = 0; ks < 2; ++ks) {
      const int col = (lane >> 4) * 8 + ks * 32;
      bf16x8 af[4], bfr[4];
#pragma unroll
      for (int mt = 0; mt < 4; ++mt)
        af[mt] = *(const bf16x8*)(As + (wm + mt * 16 + (lane & 15)) * 64 + col);
#pragma unroll
      for (int nt = 0; nt < 4; ++nt)
        bfr[nt] = *(const bf16x8*)(Bs + (wn + nt * 16 + (lane & 15)) * 64 + col);
#pragma unroll
      for (int mt = 0; mt < 4; ++mt)
#pragma unroll
        for (int nt = 0; nt < 4; ++nt)
          acc[mt][nt] = MFMA16(af[mt], bfr[nt], acc[mt][nt]);
    }
  }

  float bv[4];
#pragma unroll
  for (int nt = 0; nt < 4; ++nt)
    bv[nt] = bias[n0 + wn + nt * 16 + (lane & 15)];
#pragma unroll
  for (int mt = 0; mt < 4; ++mt)
#pragma unroll
    for (int nt = 0; nt < 4; ++nt)
#pragma unroll
      for (int r = 0; r < 4; ++r) {
        int m = m0 + wm + mt * 16 + (lane >> 4) * 4 + r;
        int n = n0 + wn + nt * 16 + (lane & 15);
        float v = acc[mt][nt][r] + bv[nt];
        if (OUT_BF16)
          ((u16*)Cout)[(size_t)m * N + n] = f2bf(v);
        else
          ((float*)Cout)[(size_t)m * N + n] = v;
      }
}

// ---------------- flash attention (v4: 8 waves x 16 q-rows, MFMA row-sum) ----------
// qkv[B*T][3072] bf16: q at col h*64, k at 1024+h*64, v at 2048+h*64.
// grid (T/128, 16 heads, B); 8 waves x 16 q-rows; KV tiles of 64 keys, double-buffered.
#define T_SEQ 2048
#define ROWQKV 3072
#define SCL 0.180336880f  /* (1/sqrt(64)) * log2(e) */

__global__ __launch_bounds__(512) void attn_fwd(
    const u16* __restrict__ qkv, const int* __restrict__ mask,
    u16* __restrict__ att) {
  __shared__ __align__(16) u16 Ks[2][64 * 64];  // [key][dk], XOR-swizzled s=row&7
  __shared__ __align__(16) u16 Vt[2][64 * 64];  // [d][key],  XOR-swizzled s=row^(row>>3)
  __shared__ __align__(16) u16 Ps[8][16 * 72];  // per-wave P tile [q][key] padded
  __shared__ u16 mk[T_SEQ];

  const int tid = threadIdx.x;
  const int lane = tid & 63;
  const int wave = tid >> 6;
  const int r15 = lane & 15;
  const int g = lane >> 4;
  const int h = blockIdx.y;
  const int b = blockIdx.z;
  const int q0 = blockIdx.x * 128 + wave * 16;
  const size_t rowb = (size_t)b * T_SEQ;

  for (int i = tid; i < T_SEQ; i += 512)
    mk[i] = (u16)(mask[b * T_SEQ + i] != 0);

  // hoist Q fragments (A-operand of QK^T): 16 q-rows per wave
  bf16x8 aq[2];
#pragma unroll
  for (int ks = 0; ks < 2; ++ks)
    aq[ks] = *(const bf16x8*)(qkv +
        (rowb + q0 + r15) * ROWQKV + h * 64 + g * 8 + ks * 32);

  // bf16 1.0 splat for the row-sum MFMA (B-operand of ones)
  bf16x8 ones;
#pragma unroll
  for (int j = 0; j < 8; ++j) ones[j] = (short)0x3F80;

  float mrun[4];
  f32x4 accO[4] = {};
  f32x4 ssum = {};  // row sums accumulated via MFMA (rescaled like accO)
#pragma unroll
  for (int r = 0; r < 4; ++r) mrun[r] = -INFINITY;

  bf16x8 vr0;  // V prefetch register (512 thr x 16B = 8KB tile)

#define ISSUE_K(ktile, buf)                                                    \
  {                                                                            \
    int L = wave * 1024 + lane * 16;                                           \
    int row = L >> 7;                                                          \
    int cb = L & 127;                                                          \
    int scb = cb ^ ((row & 7) << 4); /* pre-swizzled global source */          \
    gload_lds16((const char*)qkv +                                             \
                    ((rowb + (ktile) + row) * ROWQKV + 1024 + h * 64) * 2 + scb, \
                (char*)&Ks[buf][0] + wave * 1024);                             \
  }

#define LOAD_V(ktile)                                                          \
  vr0 = *(const bf16x8*)(qkv + (rowb + (ktile) + (tid >> 3)) * ROWQKV + 2048 + \
                         h * 64 + (tid & 7) * 8);

#define WRITE_V(buf)                                                           \
  _Pragma("unroll") for (int j = 0; j < 8; ++j) {                              \
    int row = (tid & 7) * 8 + j;                                               \
    int sv = ((row ^ (row >> 3)) & 7) << 4;                                    \
    *(u16*)((char*)&Vt[buf][0] + row * 128 + ((((tid >> 3)) * 2) ^ sv)) =      \
        (u16)vr0[j];                                                           \
  }

  // prologue: stage tile 0
  ISSUE_K(0, 0);
  LOAD_V(0);
  asm volatile("s_waitcnt vmcnt(0)" ::: "memory");
  WRITE_V(0);
  asm volatile("s_waitcnt lgkmcnt(0)" ::: "memory");
  __builtin_amdgcn_sched_barrier(0);
  __builtin_amdgcn_s_barrier();
  __builtin_amdgcn_sched_barrier(0);

  int cur = 0;
  for (int t = 0; t < T_SEQ / 64; ++t) {
    const int kt = t * 64;
    if (t < T_SEQ / 64 - 1) {  // prefetch next tile (flies during compute)
      ISSUE_K(kt + 64, cur ^ 1);
      LOAD_V(kt + 64);
    }

    // S = Q K^T (swizzled K reads)
    f32x4 s[4] = {};
#pragma unroll
    for (int ks = 0; ks < 2; ++ks) {
      bf16x8 bk[4];
#pragma unroll
      for (int nt = 0; nt < 4; ++nt) {
        int row = nt * 16 + r15;
        int cb = (g * 8 + ks * 32) * 2;
        bk[nt] = *(const bf16x8*)((const char*)&Ks[cur][0] + row * 128 +
                                  (cb ^ ((row & 7) << 4)));
      }
#pragma unroll
      for (int nt = 0; nt < 4; ++nt)
        s[nt] = MFMA16(aq[ks], bk[nt], s[nt]);
    }
    // scale (incl. log2e) + key mask
#pragma unroll
    for (int nt = 0; nt < 4; ++nt) {
      bool keep = mk[kt + nt * 16 + r15] != 0;
#pragma unroll
      for (int r = 0; r < 4; ++r)
        s[nt][r] = keep ? s[nt][r] * SCL : -1e9f;
    }
    // online softmax per q-row: max via 16-lane shuffle tree (sum comes via MFMA)
#pragma unroll
    for (int r = 0; r < 4; ++r) {
      float mx = fmaxf(fmaxf(s[0][r], s[1][r]), fmaxf(s[2][r], s[3][r]));
#pragma unroll
      for (int sh = 1; sh < 16; sh <<= 1)
        mx = fmaxf(mx, __shfl_xor(mx, sh));
      float mo = mrun[r];
      float mn = fmaxf(mo, mx);
      float fac = exp2f(mo - mn);
#pragma unroll
      for (int nt = 0; nt < 4; ++nt)
        s[nt][r] = exp2f(s[nt][r] - mn);
      mrun[r] = mn;
      ssum[r] *= fac;
#pragma unroll
      for (int nt = 0; nt < 4; ++nt)
        accO[nt][r] *= fac;
    }
    // P -> per-wave LDS (same wave consumes; compiler inserts lgkm wait)
    u16* Pw = &Ps[wave][0];
#pragma unroll
    for (int nt = 0; nt < 4; ++nt)
#pragma unroll
      for (int r = 0; r < 4; ++r)
        Pw[(g * 4 + r) * 72 + nt * 16 + r15] = f2bf(s[nt][r]);
    // O += P V ; ssum += P 1 (swizzled V reads)
#pragma unroll
    for (int ks = 0; ks < 2; ++ks) {
      const int col = g * 8 + ks * 32;
      bf16x8 ap = *(const bf16x8*)(Pw + r15 * 72 + col);
      bf16x8 bv[4];
#pragma unroll
      for (int nt = 0; nt < 4; ++nt) {
        int row = nt * 16 + r15;
        int sv = ((row ^ (row >> 3)) & 7) << 4;
        bv[nt] = *(const bf16x8*)((const char*)&Vt[cur][0] + row * 128 +
                                  ((col * 2) ^ sv));
      }
#pragma unroll
      for (int nt = 0; nt < 4; ++nt)
        accO[nt] = MFMA16(ap, bv[nt], accO[nt]);
      ssum = MFMA16(ap, ones, ssum);
    }

    if (t < T_SEQ / 64 - 1) {
      asm volatile("s_waitcnt vmcnt(0)" ::: "memory");
      WRITE_V(cur ^ 1);
      asm volatile("s_waitcnt lgkmcnt(0)" ::: "memory");
      __builtin_amdgcn_sched_barrier(0);
      __builtin_amdgcn_s_barrier();
      __builtin_amdgcn_sched_barrier(0);
      cur ^= 1;
    }
  }

  // epilogue: divide by MFMA-accumulated row sum
#pragma unroll
  for (int r = 0; r < 4; ++r) {
    float inv = 1.f / ssum[r];
#pragma unroll
    for (int nt = 0; nt < 4; ++nt) {
      int q = q0 + g * 4 + r;
      int d = h * 64 + nt * 16 + r15;
      att[(rowb + q) * 1024 + d] = f2bf(accO[nt][r] * inv);
    }
  }
#undef ISSUE_K
#undef LOAD_V
#undef WRITE_V
}

// ---------------- launch ----------------
extern "C" void kernel_launch(void* const* d_in, const int* in_sizes, int n_in,
                              void* d_out, int out_size, void* d_ws, size_t ws_size,
                              hipStream_t stream) {
  const float* x = (const float*)d_in[0];     // [2,2048,1024] f32
  const int* mask = (const int*)d_in[1];      // [2,1,1,2048] int32
  const float* Wqkv = (const float*)d_in[2];  // [1024,3072] f32
  const float* bqkv = (const float*)d_in[3];  // [3072] f32
  const float* Wout = (const float*)d_in[4];  // [1024,1024] f32
  const float* bout = (const float*)d_in[5];  // [1024] f32
  float* out = (float*)d_out;                 // [2,2048,1024] f32

  const int B = 2, T = 2048, H = 1024, M = B * T;

  u16* qkv = (u16*)d_ws;
  u16* xa = qkv + (size_t)M * 3 * H;
  u16* WtQ = xa + (size_t)M * H;
  u16* WtO = WtQ + (size_t)3 * H * H;

  cvt_f32_bf16<<<(M * H / 4 + 255) / 256, 256, 0, stream>>>(x, xa, M * H / 4);
  transpose_f32_bf16<<<dim3(3 * H / 32, H / 32), 256, 0, stream>>>(Wqkv, WtQ, H, 3 * H);
  transpose_f32_bf16<<<dim3(H / 32, H / 32), 256, 0, stream>>>(Wout, WtO, H, H);
  gemm_bf16<true><<<dim3(3 * H / 128, M / 128), 256, 0, stream>>>(xa, WtQ, bqkv, qkv, M, 3 * H, H);
  attn_fwd<<<dim3(T / 128, 16, B), 512, 0, stream>>>(qkv, mask, xa);
  gemm_bf16<false><<<dim3(H / 128, M / 128), 256, 0, stream>>>(xa, WtO, bout, out, M, H, H);
}